// Round 4
// baseline (202.959 us; speedup 1.0000x reference)
//
#include <hip/hip_runtime.h>
#include <hip/hip_fp16.h>

// GLOBE_61864708931733 — R4: kill spills, raise occupancy, trim VALU.
// R3 post-mortem: WRITE_SIZE=13.9MB = scratch spills (weight frags > 128 VGPR
// allocation), occupancy grid-limited at 2 waves/SIMD, 45% VALU idle.
// Changes:
//  - prep kernel packs W2/W3 (plain f16, pre-scaled by 2*log2e) into MFMA
//    A-frag order in d_ws; main kernel streams them per chunk (L1-hot,
//    coalesced 1KB/load). W1/Wout keep hi/lo f16 split in regs (their error
//    is the systematic one: constant feature channels / direct output path).
//  - biases pre-scaled in d_ws, folded into MFMA accumulator INIT (no adds).
//  - tanh: exp2 directly on the pre-scaled accumulator, fma(-2,rcp,1).
//  - 2 waves per target (4 chunks each), cross-wave combine via 1 syncthreads.
//    4096 waves; __launch_bounds__(128,3) -> ~155 VGPR, 12 waves/CU.
//  - hbuf: 128B stride + XOR-granule swizzle (16KB/block); geometry passed to
//    the epilogue via __shfl instead of LDS.

#define N_T 2048
#define N_S 512
#define BLK 128
#define SCALE 2.885390081777927f   // 2*log2(e)

typedef _Float16 f16x8 __attribute__((ext_vector_type(8)));
typedef float f32x4 __attribute__((ext_vector_type(4)));
typedef unsigned short u16;
typedef unsigned int u32;

__device__ __forceinline__ f16x8 pack8h(const float t[8]) {
    union { f16x8 v; __half2 h2[4]; } p;
    p.h2[0] = __floats2half2_rn(t[0], t[1]);
    p.h2[1] = __floats2half2_rn(t[2], t[3]);
    p.h2[2] = __floats2half2_rn(t[4], t[5]);
    p.h2[3] = __floats2half2_rn(t[6], t[7]);
    return p.v;
}

__device__ __forceinline__ void split8(const float t[8], f16x8& hi, f16x8& lo) {
    float rh[8], rl[8];
    #pragma unroll
    for (int j = 0; j < 8; ++j) {
        float h = (float)(_Float16)t[j];   // RTN f32->f16->f32
        rh[j] = h;
        rl[j] = t[j] - h;                  // exact residual, fits f16
    }
    hi = pack8h(rh);
    lo = pack8h(rl);
}

// Input x is already SCALE*y; tanh(y) = 1 - 2/(exp2(x)+1).
__device__ __forceinline__ float tanh_s(float x) {
    float e = __builtin_amdgcn_exp2f(x);
    return fmaf(-2.0f, __builtin_amdgcn_rcpf(e + 1.0f), 1.0f);
}

__device__ __forceinline__ f32x4 mfma16h(f16x8 a, f16x8 b, f32x4 c) {
    return __builtin_amdgcn_mfma_f32_16x16x32_f16(a, b, c, 0, 0, 0);
}

__device__ __forceinline__ void store4h(u16* dst, float t0, float t1, float t2, float t3) {
    __half2 ha = __floats2half2_rn(t0, t1);
    __half2 hb = __floats2half2_rn(t2, t3);
    uint2 w;
    w.x = *(u32*)&ha;
    w.y = *(u32*)&hb;
    *(uint2*)dst = w;
}

// ---- prep: pack W2/W3 into A-frag order (f16, pre-scaled) + scaled biases ----
// ws layout: uint4 frags [L=2][ks=2][mt=4][lane=64] (16 KB), then f32 sbias[3][64].
__global__ __launch_bounds__(256) void prep_kernel(
    const float* __restrict__ W2, const float* __restrict__ W3,
    const float* __restrict__ b1, const float* __restrict__ b2,
    const float* __restrict__ b3, float* __restrict__ ws)
{
    const int e = blockIdx.x * 256 + threadIdx.x;   // 0..1023
    const int fid = e >> 6, lane = e & 63;
    const int L = fid >> 3, ks = (fid >> 2) & 1, mt = fid & 3;
    const int q = lane >> 4, l15 = lane & 15;
    const float* W = L ? W3 : W2;
    float tmp[8];
    #pragma unroll
    for (int j = 0; j < 8; ++j)
        tmp[j] = W[(ks * 32 + q * 8 + j) * 64 + mt * 16 + l15] * SCALE;
    union { f16x8 v; uint4 u; } pk;
    pk.v = pack8h(tmp);
    ((uint4*)ws)[e] = pk.u;

    if (blockIdx.x == 0 && threadIdx.x < 192) {
        const int Lb = threadIdx.x >> 6, i = threadIdx.x & 63;
        const float* b = (Lb == 0) ? b1 : ((Lb == 1) ? b2 : b3);
        ws[4096 + threadIdx.x] = b[i] * SCALE;
    }
}

__global__ __launch_bounds__(BLK, 3) void globe_mfma(
    const float* __restrict__ pts, const float* __restrict__ ctr,
    const float* __restrict__ nrm, const float* __restrict__ areas,
    const float* __restrict__ rlen,
    const float* __restrict__ W1, const float* __restrict__ Wout,
    const float* __restrict__ bout,
    const float* __restrict__ p_scale, const float* __restrict__ p_bias,
    const float* __restrict__ v_scale, const float* __restrict__ v_bias,
    const float* __restrict__ ws,
    float* __restrict__ out)
{
    // Swizzled activation buffer: row stride 64 f16 (128 B), 16B granule g
    // stored at g ^ (row & 7). Per-wave slab; no cross-wave use.
    __shared__ __align__(16) u16 hbuf[2][64][64];
    __shared__ uint4 zbufs[2];
    __shared__ float xred[4];

    const int tid  = threadIdx.x;
    const int lane = tid & 63;
    const int wv   = tid >> 6;
    const int l15  = lane & 15;
    const int q    = lane >> 4;
    const int t    = blockIdx.x;

    if (lane == 0) zbufs[wv] = make_uint4(0u, 0u, 0u, 0u);

    const uint4* __restrict__ wsA = (const uint4*)ws;          // A-frags
    const float4* __restrict__ wsb4 = (const float4*)(ws + 4096); // scaled biases

    // ---- resident weights: W1 hi/lo (scaled), Wout hi/lo (raw) ----
    f16x8 w1hi[4], w1lo[4], wohi[2], wolo[2];
    {
        float tmp[8];
        #pragma unroll
        for (int mt = 0; mt < 4; ++mt) {
            const int m = mt * 16 + l15;
            if (q == 0) {
                #pragma unroll
                for (int j = 0; j < 7; ++j) tmp[j] = W1[j * 64 + m] * SCALE;
                tmp[7] = 0.f;
            } else {
                #pragma unroll
                for (int j = 0; j < 8; ++j) tmp[j] = 0.f;
            }
            split8(tmp, w1hi[mt], w1lo[mt]);
        }
        #pragma unroll
        for (int ks = 0; ks < 2; ++ks) {
            #pragma unroll
            for (int j = 0; j < 8; ++j)
                tmp[j] = (l15 < 3) ? Wout[(ks * 32 + q * 8 + j) * 3 + l15] : 0.f;
            split8(tmp, wohi[ks], wolo[ks]);
        }
    }

    f32x4 co_init = (f32x4){0.f, 0.f, 0.f, 0.f};
    if (q == 0) { co_init[0] = bout[0]; co_init[1] = bout[1]; co_init[2] = bout[2]; }

    const float px = pts[3 * t + 0], py = pts[3 * t + 1], pz = pts[3 * t + 2];
    const float invL0 = __builtin_amdgcn_rcpf(rlen[0]);
    const float invL1 = __builtin_amdgcn_rcpf(rlen[1]);

    u16* hb = &hbuf[wv][0][0];
    const int sw = (l15 & 7);   // swizzle key for this lane's B-rows

    float accp = 0.f, avx = 0.f, avy = 0.f, avz = 0.f;

    #pragma unroll 1
    for (int i = 0; i < 4; ++i) {
        const int s = (wv * 4 + i) * 64 + lane;
        // ---- per-pair geometry + raw features (lane = pair) ----
        const float cx = ctr[3 * s + 0], cy = ctr[3 * s + 1], cz = ctr[3 * s + 2];
        const float snx = nrm[3 * s + 0], sny = nrm[3 * s + 1], snz = nrm[3 * s + 2];
        const float ar = areas[s];
        const float rvx = px - cx, rvy = py - cy, rvz = pz - cz;
        const float r2 = rvx * rvx + rvy * rvy + rvz * rvz;
        const float r2e = r2 + 1e-8f;
        const float rinv = __builtin_amdgcn_rsqf(r2e);
        const float r = r2e * rinv;
        const float rhx = rvx * rinv, rhy = rvy * rinv, rhz = rvz * rinv;
        const float cth = rhx * snx + rhy * sny + rhz * snz;
        const float c2 = cth * cth;
        float f[8];
        f[0] = __builtin_amdgcn_rcpf(fmaf(r, invL0, 1.0f));
        f[1] = __builtin_amdgcn_rcpf(fmaf(r, invL1, 1.0f));
        f[2] = 1.0f;
        f[3] = cth;
        f[4] = fmaf(1.5f, c2, -0.5f);
        f[5] = cth * fmaf(2.5f, c2, -1.5f);
        f[6] = __logf(ar);
        f[7] = 0.f;
        const float decay = ar * __builtin_amdgcn_rcpf(r2 + 1.0f);

        // feature row: granule 0 -> phys (lane&7)
        *(f16x8*)(hb + lane * 64 + ((lane & 7) << 3)) = pack8h(f);

        // ---- layer 1: W1 hi/lo regs; K=32 with only octet 0 live ----
        {
            const u16* zp = (const u16*)&zbufs[wv];
            #pragma unroll
            for (int nh = 0; nh < 2; ++nh) {
                f32x4 c[4][2];
                #pragma unroll
                for (int mt = 0; mt < 4; ++mt) {
                    const float4 bv = wsb4[0 * 16 + mt * 4 + q];
                    c[mt][0] = (f32x4){bv.x, bv.y, bv.z, bv.w};
                    c[mt][1] = c[mt][0];
                }
                const int r0 = (nh * 2 + 0) * 16 + l15, r1 = (nh * 2 + 1) * 16 + l15;
                const u16* s0 = (q == 0) ? (hb + r0 * 64 + (sw << 3)) : zp;
                const u16* s1 = (q == 0) ? (hb + r1 * 64 + (sw << 3)) : zp;
                const f16x8 bf0 = *(const f16x8*)s0;
                const f16x8 bf1 = *(const f16x8*)s1;
                #pragma unroll
                for (int mt = 0; mt < 4; ++mt) {
                    c[mt][0] = mfma16h(w1hi[mt], bf0, c[mt][0]);
                    c[mt][1] = mfma16h(w1hi[mt], bf1, c[mt][1]);
                    c[mt][0] = mfma16h(w1lo[mt], bf0, c[mt][0]);
                    c[mt][1] = mfma16h(w1lo[mt], bf1, c[mt][1]);
                }
                #pragma unroll
                for (int mt = 0; mt < 4; ++mt)
                    #pragma unroll
                    for (int n = 0; n < 2; ++n) {
                        const int rr = (nh * 2 + n) * 16 + l15;
                        u16* dst = hb + rr * 64 + ((((2 * mt + (q >> 1)) ^ sw)) << 3) + (q & 1) * 4;
                        store4h(dst, tanh_s(c[mt][n][0]), tanh_s(c[mt][n][1]),
                                     tanh_s(c[mt][n][2]), tanh_s(c[mt][n][3]));
                    }
            }
        }

        // ---- layers 2 & 3: A-frags streamed from ws (L1-hot) ----
        #pragma unroll
        for (int L = 0; L < 2; ++L) {
            #pragma unroll
            for (int nh = 0; nh < 2; ++nh) {
                f16x8 af[8];
                #pragma unroll
                for (int fi = 0; fi < 8; ++fi) {
                    union { uint4 u; f16x8 v; } ld;
                    ld.u = wsA[(L * 8 + fi) * 64 + lane];
                    af[fi] = ld.v;
                }
                f32x4 c[4][2];
                #pragma unroll
                for (int mt = 0; mt < 4; ++mt) {
                    const float4 bv = wsb4[(L + 1) * 16 + mt * 4 + q];
                    c[mt][0] = (f32x4){bv.x, bv.y, bv.z, bv.w};
                    c[mt][1] = c[mt][0];
                }
                #pragma unroll
                for (int ks = 0; ks < 2; ++ks) {
                    const int r0 = (nh * 2 + 0) * 16 + l15, r1 = (nh * 2 + 1) * 16 + l15;
                    const int goff = ((4 * ks + q) ^ sw) << 3;
                    const f16x8 bf0 = *(const f16x8*)(hb + r0 * 64 + goff);
                    const f16x8 bf1 = *(const f16x8*)(hb + r1 * 64 + goff);
                    #pragma unroll
                    for (int mt = 0; mt < 4; ++mt) {
                        c[mt][0] = mfma16h(af[ks * 4 + mt], bf0, c[mt][0]);
                        c[mt][1] = mfma16h(af[ks * 4 + mt], bf1, c[mt][1]);
                    }
                }
                #pragma unroll
                for (int mt = 0; mt < 4; ++mt)
                    #pragma unroll
                    for (int n = 0; n < 2; ++n) {
                        const int rr = (nh * 2 + n) * 16 + l15;
                        u16* dst = hb + rr * 64 + ((((2 * mt + (q >> 1)) ^ sw)) << 3) + (q & 1) * 4;
                        store4h(dst, tanh_s(c[mt][n][0]), tanh_s(c[mt][n][1]),
                                     tanh_s(c[mt][n][2]), tanh_s(c[mt][n][3]));
                    }
            }
        }

        // ---- output layer (Wout hi/lo regs) + epilogue via shuffles ----
        #pragma unroll
        for (int nh = 0; nh < 2; ++nh) {
            f32x4 co[2];
            co[0] = co_init; co[1] = co_init;
            #pragma unroll
            for (int ks = 0; ks < 2; ++ks) {
                const int r0 = (nh * 2 + 0) * 16 + l15, r1 = (nh * 2 + 1) * 16 + l15;
                const int goff = ((4 * ks + q) ^ sw) << 3;
                const f16x8 bf0 = *(const f16x8*)(hb + r0 * 64 + goff);
                const f16x8 bf1 = *(const f16x8*)(hb + r1 * 64 + goff);
                co[0] = mfma16h(wohi[ks], bf0, co[0]);
                co[1] = mfma16h(wohi[ks], bf1, co[1]);
                co[0] = mfma16h(wolo[ks], bf0, co[0]);
                co[1] = mfma16h(wolo[ks], bf1, co[1]);
            }
            #pragma unroll
            for (int n = 0; n < 2; ++n) {
                const int p = (nh * 2 + n) * 16 + l15;
                const float d  = __shfl(decay, p);
                const float rx = __shfl(rhx, p), ry = __shfl(rhy, p), rz = __shfl(rhz, p);
                const float sx = __shfl(snx, p), sy = __shfl(sny, p), sz = __shfl(snz, p);
                if (q == 0) {
                    const float o0 = co[n][0], o1 = co[n][1], o2 = co[n][2];
                    accp = fmaf(o0, d, accp);
                    avx  = fmaf(fmaf(o1, rx, o2 * sx), d, avx);
                    avy  = fmaf(fmaf(o1, ry, o2 * sy), d, avy);
                    avz  = fmaf(fmaf(o1, rz, o2 * sz), d, avz);
                }
            }
        }
    }

    // ---- reduce across the 16 accumulating lanes ----
    #pragma unroll
    for (int off = 8; off > 0; off >>= 1) {
        accp += __shfl_down(accp, off);
        avx  += __shfl_down(avx,  off);
        avy  += __shfl_down(avy,  off);
        avz  += __shfl_down(avz,  off);
    }

    // ---- cross-wave combine ----
    if (wv == 1 && lane == 0) {
        xred[0] = accp; xred[1] = avx; xred[2] = avy; xred[3] = avz;
    }
    __syncthreads();
    if (wv == 0 && lane == 0) {
        accp += xred[0]; avx += xred[1]; avy += xred[2]; avz += xred[3];
        const float ps = p_scale[0], pb = p_bias[0];
        const float vs = v_scale[0], vb = v_bias[0];
        out[4 * t + 0] = fmaf(accp, ps, pb);
        out[4 * t + 1] = fmaf(avx, vs, vb);
        out[4 * t + 2] = fmaf(avy, vs, vb);
        out[4 * t + 3] = fmaf(avz, vs, vb);
    }
}

extern "C" void kernel_launch(void* const* d_in, const int* in_sizes, int n_in,
                              void* d_out, int out_size, void* d_ws, size_t ws_size,
                              hipStream_t stream) {
    (void)in_sizes; (void)n_in; (void)ws_size; (void)out_size;
    const float* pts   = (const float*)d_in[0];
    const float* ctr   = (const float*)d_in[1];
    const float* nrm   = (const float*)d_in[2];
    const float* areas = (const float*)d_in[3];
    const float* rlen  = (const float*)d_in[4];
    const float* W1    = (const float*)d_in[5];
    const float* b1    = (const float*)d_in[6];
    const float* W2    = (const float*)d_in[7];
    const float* b2    = (const float*)d_in[8];
    const float* W3    = (const float*)d_in[9];
    const float* b3    = (const float*)d_in[10];
    const float* Wout  = (const float*)d_in[11];
    const float* bout  = (const float*)d_in[12];
    const float* ps    = (const float*)d_in[13];
    const float* pb    = (const float*)d_in[14];
    const float* vs    = (const float*)d_in[15];
    const float* vb    = (const float*)d_in[16];
    float* ws = (float*)d_ws;

    prep_kernel<<<4, 256, 0, stream>>>(W2, W3, b1, b2, b3, ws);
    globe_mfma<<<N_T, BLK, 0, stream>>>(
        pts, ctr, nrm, areas, rlen, W1, Wout, bout,
        ps, pb, vs, vb, ws, (float*)d_out);
}

// Round 6
// 149.447 us; speedup vs baseline: 1.3581x; 1.3581x over previous
//
#include <hip/hip_runtime.h>
#include <hip/hip_fp16.h>

// GLOBE_61864708931733 — R6: R3-proven skeleton + zero-SROA-hazard weights.
// History: R3 passed 103us but spilled (VGPR_Count 128 << demand ~200, 21 MB
// scratch traffic). R4/R5 tried to fix occupancy/spills but introduced SROA
// hazards (unions, pointer ternaries, array params) -> 84-reg alloc + 338 MB
// scratch (R4), NaN (R5). R6: exact R3 launch shape (128-thr block, wave owns
// target, 8 chunks), with:
//  - no unions / no array-typed fn params / no pointer selects anywhere;
//  - W2/W3 plain f16 prescaled by 2*log2e (R4-proven numerics, -64 VGPR);
//  - W1 hi/lo (systematic error path: constant feature channels), Wout hi/lo;
//  - b1 folded into W1-layer acc init; b2/b3 float4 loads scaled inline;
//  - acc one 16-pair row-group at a time (c[4] = 16 VGPR);
//  - layer-1 zero B-frag via value cndmask (no LDS zbuf).
// Peak live ~190 < 256 (__launch_bounds__(128,2)) -> expect zero spills.

#define N_T 2048
#define N_S 512
#define BLK 128
#define WPB 2
#define SCALE 2.885390081777927f   // 2*log2(e)

typedef _Float16 f16;
typedef _Float16 f16x8 __attribute__((ext_vector_type(8)));
typedef _Float16 f16x4 __attribute__((ext_vector_type(4)));
typedef float f32x4 __attribute__((ext_vector_type(4)));
typedef unsigned short u16;

// Input x is already SCALE*y; tanh(y) = 1 - 2/(exp2(x)+1). Saturates exactly.
__device__ __forceinline__ float tanh_s(float x) {
    float e = __builtin_amdgcn_exp2f(x);
    return fmaf(-2.0f, __builtin_amdgcn_rcpf(e + 1.0f), 1.0f);
}

__device__ __forceinline__ f32x4 mfma16h(f16x8 a, f16x8 b, f32x4 c) {
    return __builtin_amdgcn_mfma_f32_16x16x32_f16(a, b, c, 0, 0, 0);
}

// One 64->64 tanh dense layer. WARR: f16x8[8], [ks*4+mt]. BPTR: float4* raw bias.
// Row-group n4 at a time: reads (both ks) of a row complete before its writes;
// other row-groups untouched -> in-place safe (per-wave LDS, in-order DS pipe).
#define DENSE_LAYER(WARR, BPTR)                                                \
    {                                                                          \
        _Pragma("unroll")                                                      \
        for (int n4 = 0; n4 < 4; ++n4) {                                       \
            const int row = n4 * 16 + l15;                                     \
            const f16x8 bfa = *(const f16x8*)&hb[row][q * 8];                  \
            const f16x8 bfb = *(const f16x8*)&hb[row][32 + q * 8];             \
            f32x4 c[4];                                                        \
            _Pragma("unroll")                                                  \
            for (int mt = 0; mt < 4; ++mt) {                                   \
                const float4 b = BPTR[mt * 4 + q];                             \
                c[mt] = (f32x4){b.x * SCALE, b.y * SCALE,                      \
                                b.z * SCALE, b.w * SCALE};                     \
            }                                                                  \
            _Pragma("unroll")                                                  \
            for (int mt = 0; mt < 4; ++mt)                                     \
                c[mt] = mfma16h(WARR[mt], bfa, c[mt]);                         \
            _Pragma("unroll")                                                  \
            for (int mt = 0; mt < 4; ++mt)                                     \
                c[mt] = mfma16h(WARR[4 + mt], bfb, c[mt]);                     \
            _Pragma("unroll")                                                  \
            for (int mt = 0; mt < 4; ++mt) {                                   \
                f16x4 o;                                                       \
                o[0] = (f16)tanh_s(c[mt][0]);                                  \
                o[1] = (f16)tanh_s(c[mt][1]);                                  \
                o[2] = (f16)tanh_s(c[mt][2]);                                  \
                o[3] = (f16)tanh_s(c[mt][3]);                                  \
                *(f16x4*)&hb[row][mt * 16 + q * 4] = o;                        \
            }                                                                  \
        }                                                                      \
    }

__global__ __launch_bounds__(BLK, 2) void globe_mfma(
    const float* __restrict__ pts, const float* __restrict__ ctr,
    const float* __restrict__ nrm, const float* __restrict__ areas,
    const float* __restrict__ rlen,
    const float* __restrict__ W1, const float* __restrict__ b1,
    const float* __restrict__ W2, const float* __restrict__ b2,
    const float* __restrict__ W3, const float* __restrict__ b3,
    const float* __restrict__ Wout, const float* __restrict__ bout,
    const float* __restrict__ p_scale, const float* __restrict__ p_bias,
    const float* __restrict__ v_scale, const float* __restrict__ v_bias,
    float* __restrict__ out)
{
    __shared__ __align__(16) u16 hbuf[WPB][64][72];   // activations, 144 B row stride
    __shared__ __align__(16) float geom[WPB][64][8];  // decay,rhat | normal per pair

    const int tid  = threadIdx.x;
    const int lane = tid & 63;
    const int wv   = tid >> 6;
    const int l15  = lane & 15;
    const int q    = lane >> 4;
    const int t    = blockIdx.x * WPB + wv;

    // ---- pack A-frags (all static element writes; no unions) ----
    f16x8 w1h[4], w1l[4];     // scaled, hi/lo split; zero for q>0 lanes & k=7
    f16x8 w2f[8], w3f[8];     // scaled, plain f16; [ks*4+mt]
    f16x8 woh[2], wol[2];     // unscaled, hi/lo split; rows >=3 zero
    #pragma unroll
    for (int mt = 0; mt < 4; ++mt) {
        f16x8 vh, vl;
        #pragma unroll
        for (int j = 0; j < 8; ++j) {
            const float x = (q == 0 && j < 7) ? W1[j * 64 + mt * 16 + l15] * SCALE : 0.f;
            const f16 h = (f16)x;
            vh[j] = h;
            vl[j] = (f16)(x - (float)h);
        }
        w1h[mt] = vh; w1l[mt] = vl;
    }
    #pragma unroll
    for (int ks = 0; ks < 2; ++ks)
        #pragma unroll
        for (int mt = 0; mt < 4; ++mt) {
            f16x8 v;
            #pragma unroll
            for (int j = 0; j < 8; ++j)
                v[j] = (f16)(W2[(ks * 32 + q * 8 + j) * 64 + mt * 16 + l15] * SCALE);
            w2f[ks * 4 + mt] = v;
        }
    #pragma unroll
    for (int ks = 0; ks < 2; ++ks)
        #pragma unroll
        for (int mt = 0; mt < 4; ++mt) {
            f16x8 v;
            #pragma unroll
            for (int j = 0; j < 8; ++j)
                v[j] = (f16)(W3[(ks * 32 + q * 8 + j) * 64 + mt * 16 + l15] * SCALE);
            w3f[ks * 4 + mt] = v;
        }
    #pragma unroll
    for (int ks = 0; ks < 2; ++ks) {
        f16x8 vh, vl;
        #pragma unroll
        for (int j = 0; j < 8; ++j) {
            const float x = (l15 < 3) ? Wout[(ks * 32 + q * 8 + j) * 3 + l15] : 0.f;
            const f16 h = (f16)x;
            vh[j] = h;
            vl[j] = (f16)(x - (float)h);
        }
        woh[ks] = vh; wol[ks] = vl;
    }

    const float px = pts[3 * t + 0], py = pts[3 * t + 1], pz = pts[3 * t + 2];
    const float invL0 = __builtin_amdgcn_rcpf(rlen[0]);
    const float invL1 = __builtin_amdgcn_rcpf(rlen[1]);
    f32x4 co_init = (f32x4){0.f, 0.f, 0.f, 0.f};
    if (q == 0) { co_init[0] = bout[0]; co_init[1] = bout[1]; co_init[2] = bout[2]; }

    const float4* __restrict__ b1v4 = (const float4*)b1;
    const float4* __restrict__ b2v4 = (const float4*)b2;
    const float4* __restrict__ b3v4 = (const float4*)b3;

    u16 (*hb)[72] = hbuf[wv];
    float (*gm)[8] = geom[wv];
    const f16x8 fzero = (f16x8){0, 0, 0, 0, 0, 0, 0, 0};

    float accp = 0.f, avx = 0.f, avy = 0.f, avz = 0.f;

    #pragma unroll 1
    for (int ch = 0; ch < 8; ++ch) {
        const int s = ch * 64 + lane;
        // ---- per-pair geometry + features (lane = pair) ----
        const float cx = ctr[3 * s + 0], cy = ctr[3 * s + 1], cz = ctr[3 * s + 2];
        const float snx = nrm[3 * s + 0], sny = nrm[3 * s + 1], snz = nrm[3 * s + 2];
        const float ar = areas[s];
        const float rvx = px - cx, rvy = py - cy, rvz = pz - cz;
        const float r2 = rvx * rvx + rvy * rvy + rvz * rvz;
        const float r2e = r2 + 1e-8f;
        const float rinv = __builtin_amdgcn_rsqf(r2e);
        const float r = r2e * rinv;
        const float rhx = rvx * rinv, rhy = rvy * rinv, rhz = rvz * rinv;
        const float cth = rhx * snx + rhy * sny + rhz * snz;
        const float c2 = cth * cth;
        const float decay = ar * __builtin_amdgcn_rcpf(r2 + 1.0f);
        {
            f16x8 fv;
            fv[0] = (f16)(__builtin_amdgcn_rcpf(fmaf(r, invL0, 1.0f)));
            fv[1] = (f16)(__builtin_amdgcn_rcpf(fmaf(r, invL1, 1.0f)));
            fv[2] = (f16)1.0f;
            fv[3] = (f16)cth;
            fv[4] = (f16)fmaf(1.5f, c2, -0.5f);
            fv[5] = (f16)(cth * fmaf(2.5f, c2, -1.5f));
            fv[6] = (f16)__logf(ar);
            fv[7] = (f16)0.0f;
            *(f16x8*)&hb[lane][0] = fv;
        }
        *(float4*)&gm[lane][0] = make_float4(decay, rhx, rhy, rhz);
        *(float4*)&gm[lane][4] = make_float4(snx, sny, snz, 0.f);

        // ---- layer 1: K=32 with only k=0..7 live (q>0 contributes zeros) ----
        #pragma unroll
        for (int n4 = 0; n4 < 4; ++n4) {
            const int row = n4 * 16 + l15;
            const f16x8 lv = *(const f16x8*)&hb[row][0];
            const f16x8 bf = (q == 0) ? lv : fzero;   // value select, not pointer
            f32x4 c[4];
            #pragma unroll
            for (int mt = 0; mt < 4; ++mt) {
                const float4 b = b1v4[mt * 4 + q];
                c[mt] = (f32x4){b.x * SCALE, b.y * SCALE, b.z * SCALE, b.w * SCALE};
            }
            #pragma unroll
            for (int mt = 0; mt < 4; ++mt) c[mt] = mfma16h(w1h[mt], bf, c[mt]);
            #pragma unroll
            for (int mt = 0; mt < 4; ++mt) c[mt] = mfma16h(w1l[mt], bf, c[mt]);
            #pragma unroll
            for (int mt = 0; mt < 4; ++mt) {
                f16x4 o;
                o[0] = (f16)tanh_s(c[mt][0]);
                o[1] = (f16)tanh_s(c[mt][1]);
                o[2] = (f16)tanh_s(c[mt][2]);
                o[3] = (f16)tanh_s(c[mt][3]);
                *(f16x4*)&hb[row][mt * 16 + q * 4] = o;
            }
        }

        // ---- layers 2 & 3 ----
        DENSE_LAYER(w2f, b2v4)
        DENSE_LAYER(w3f, b3v4)

        // ---- output layer + decay-weighted accumulation ----
        #pragma unroll
        for (int n4 = 0; n4 < 4; ++n4) {
            const int row = n4 * 16 + l15;
            const f16x8 bfa = *(const f16x8*)&hb[row][q * 8];
            const f16x8 bfb = *(const f16x8*)&hb[row][32 + q * 8];
            f32x4 co = co_init;
            co = mfma16h(woh[0], bfa, co);
            co = mfma16h(wol[0], bfa, co);
            co = mfma16h(woh[1], bfb, co);
            co = mfma16h(wol[1], bfb, co);
            if (q == 0) {   // C rows 0..2 = out channels, live in lanes 0..15
                const float4 g1 = *(const float4*)&gm[row][0];
                const float4 g2 = *(const float4*)&gm[row][4];
                const float o0 = co[0], o1 = co[1], o2 = co[2];
                accp = fmaf(o0, g1.x, accp);
                avx  = fmaf(fmaf(o1, g1.y, o2 * g2.x), g1.x, avx);
                avy  = fmaf(fmaf(o1, g1.z, o2 * g2.y), g1.x, avy);
                avz  = fmaf(fmaf(o1, g1.w, o2 * g2.z), g1.x, avz);
            }
        }
    }

    // ---- reduce across the 16 accumulating lanes ----
    #pragma unroll
    for (int off = 8; off > 0; off >>= 1) {
        accp += __shfl_down(accp, off);
        avx  += __shfl_down(avx,  off);
        avy  += __shfl_down(avy,  off);
        avz  += __shfl_down(avz,  off);
    }

    if (lane == 0) {
        const float ps = p_scale[0], pb = p_bias[0];
        const float vs = v_scale[0], vb = v_bias[0];
        out[4 * t + 0] = fmaf(accp, ps, pb);
        out[4 * t + 1] = fmaf(avx, vs, vb);
        out[4 * t + 2] = fmaf(avy, vs, vb);
        out[4 * t + 3] = fmaf(avz, vs, vb);
    }
}

extern "C" void kernel_launch(void* const* d_in, const int* in_sizes, int n_in,
                              void* d_out, int out_size, void* d_ws, size_t ws_size,
                              hipStream_t stream) {
    (void)in_sizes; (void)n_in; (void)d_ws; (void)ws_size; (void)out_size;
    const float* pts   = (const float*)d_in[0];
    const float* ctr   = (const float*)d_in[1];
    const float* nrm   = (const float*)d_in[2];
    const float* areas = (const float*)d_in[3];
    const float* rlen  = (const float*)d_in[4];
    const float* W1    = (const float*)d_in[5];
    const float* b1    = (const float*)d_in[6];
    const float* W2    = (const float*)d_in[7];
    const float* b2    = (const float*)d_in[8];
    const float* W3    = (const float*)d_in[9];
    const float* b3    = (const float*)d_in[10];
    const float* Wout  = (const float*)d_in[11];
    const float* bout  = (const float*)d_in[12];
    const float* ps    = (const float*)d_in[13];
    const float* pb    = (const float*)d_in[14];
    const float* vs    = (const float*)d_in[15];
    const float* vb    = (const float*)d_in[16];

    globe_mfma<<<N_T / WPB, BLK, 0, stream>>>(
        pts, ctr, nrm, areas, rlen, W1, b1, W2, b2, W3, b3, Wout, bout,
        ps, pb, vs, vb, (float*)d_out);
}